// Round 12
// baseline (108.917 us; speedup 1.0000x reference)
//
#include <hip/hip_runtime.h>

// MVB (minimum-variance beamformer), fp32. Round 12: R10 + explicit
// software pipeline (rotating register sets, 1 chunk ahead).
//
// R10 (cache-gather, no LDS) = best total. Residual theory: chunk
// boundaries serialize -- FMA burst q blocks gather issue q+1, TA drains
// between chunks. Fix: pipeline in-thread with static rotating sets:
//   step q: load dr[q+2] (3 sets A/B/C), gather chunk q+1 (2 sets A/B),
//           FMA chunk q.
// Dependencies are register-carried; compiler inserts waitcnts (no manual
// vmcnt -- R8's lesson). No LDS, no barriers, 1 thread/px, grid 256x256.

namespace {

constexpr int kB  = 2;
constexpr int kC  = 128;
constexpr int kNS = 1024;
constexpr int kNZ = 256;
constexpr int kNX = 128;
constexpr int kZX = kNZ * kNX;        // 32768
constexpr int kTPB = 256;

// packed upper-triangular index, l <= k, 16x16 -> 136 entries
__device__ __host__ constexpr int tri(int l, int k) {
  return l * 16 - (l * (l - 1)) / 2 + (k - l);
}

struct Dr16  { float d[16]; };
struct Gth16 { float2 vv[16]; float fr[16]; };

__device__ __forceinline__ void load_dr(const float* __restrict__ drxp,
                                        int cbase, Dr16& o) {
#pragma unroll
  for (int r = 0; r < 16; ++r) o.d[r] = drxp[(size_t)(cbase + r) * kZX];
}

__device__ __forceinline__ void gather16(const float* __restrict__ rfq,
                                         const Dr16& dr, float kk, float base,
                                         Gth16& o) {
#pragma unroll
  for (int r = 0; r < 16; ++r) {
    float pos = fmaf(kk, dr.d[r], base);
    pos = fminf(fmaxf(pos, 0.0f), 1023.0f);
    int i0 = (int)pos;                   // pos >= 0: trunc == floor
    i0 = min(i0, kNS - 2);               // pos==1023 -> frac==1.0
    o.fr[r] = pos - (float)i0;
    __builtin_memcpy(&o.vv[r], rfq + r * kNS + i0, 8);   // v0,v1 adjacent
  }
}

template <bool HEAD>
__device__ __forceinline__ void fmas16(const Gth16& g, float (&F)[16],
                                       float (&win)[16], float (&head)[16],
                                       float& Sall) {
#pragma unroll
  for (int r = 0; r < 16; ++r) {
    float v = fmaf(g.fr[r], g.vv[r].y - g.vv[r].x, g.vv[r].x);
    Sall += v;
    F[0] = fmaf(v, v, F[0]);
    if constexpr (HEAD) {
#pragma unroll
      for (int d = 1; d <= r; ++d) F[d] = fmaf(v, win[r - d], F[d]);
      head[r] = v;
    } else {
#pragma unroll
      for (int d = 1; d < 16; ++d) F[d] = fmaf(v, win[(r - d) & 15], F[d]);
    }
    win[r] = v;
  }
}

// ---------------- Fused kernel: pipelined gather + window + solve ----------
__global__ __launch_bounds__(kTPB, 1) void mvb_kernel(
    const float* __restrict__ rf, const float* __restrict__ t0,
    const float* __restrict__ d_tx, const float* __restrict__ d_rx,
    const float* __restrict__ fs_p, const float* __restrict__ c0_p,
    float* __restrict__ out) {
  const int tid = threadIdx.x;
  const int b = blockIdx.x >> 7;         // 256 blocks: b in {0,1}
  const int z = ((blockIdx.x & 127) << 1) + (tid >> 7);
  const int x = tid & 127;
  const int pix = (int)((size_t)b * kZX + z * kNX + x);

  const float fs = fs_p[0];
  const float c0 = c0_p[0];
  const float kk = fs / c0;
  const float base = fs * (d_tx[pix] / c0 + t0[b]);

  const float* rfb = rfb = rf + (size_t)b * kC * kNS;
  const float* drxp = d_rx + (size_t)z * kNX + x;   // + c*kZX per channel

  float F[16], win[16], head[16];
  float Sall = 0.0f;
#pragma unroll
  for (int i = 0; i < 16; ++i) F[i] = 0.0f;

  // rotating register sets: dr A/B/C (3-deep), gather A/B (2-deep)
  Dr16 drA, drB, drC;
  Gth16 gA, gB;

#define RFQ(c) (rfb + (size_t)(c) * 16 * kNS)

  // ---- prologue ----
  load_dr(drxp, 0 * 16, drA);
  load_dr(drxp, 1 * 16, drB);
  gather16(RFQ(0), drA, kk, base, gA);

  // ---- 8 pipelined steps (chunk c FMA'd at step c) ----
  // step 0
  load_dr(drxp, 2 * 16, drC);
  gather16(RFQ(1), drB, kk, base, gB);
  fmas16<true>(gA, F, win, head, Sall);
  // step 1
  load_dr(drxp, 3 * 16, drA);
  gather16(RFQ(2), drC, kk, base, gA);
  fmas16<false>(gB, F, win, head, Sall);
  // step 2
  load_dr(drxp, 4 * 16, drB);
  gather16(RFQ(3), drA, kk, base, gB);
  fmas16<false>(gA, F, win, head, Sall);
  // step 3
  load_dr(drxp, 5 * 16, drC);
  gather16(RFQ(4), drB, kk, base, gA);
  fmas16<false>(gB, F, win, head, Sall);
  // step 4
  load_dr(drxp, 6 * 16, drA);
  gather16(RFQ(5), drC, kk, base, gB);
  fmas16<false>(gA, F, win, head, Sall);
  // step 5
  load_dr(drxp, 7 * 16, drB);
  gather16(RFQ(6), drA, kk, base, gA);
  fmas16<false>(gB, F, win, head, Sall);
  // step 6
  gather16(RFQ(7), drB, kk, base, gB);
  fmas16<false>(gA, F, win, head, Sall);
  // step 7
  fmas16<false>(gB, F, win, head, Sall);
#undef RFQ
  // now: head[i] = xf[i], win[i] = xf[112+i], F[d] = sum_j xf[j]*xf[j-d]

  // ---- assemble R (unscaled; packed upper triangle) ----
  float Ru[136];
#pragma unroll
  for (int d = 0; d < 16; ++d) {
    float t0s = 0.0f;                    // tail beyond window of l=0
#pragma unroll
    for (int i = d + 1; i < 16; ++i) t0s = fmaf(win[i - d], win[i], t0s);
    Ru[tri(0, d)] = F[d] - t0s;
#pragma unroll
    for (int l = 1; l < 16 - d; ++l)
      Ru[tri(l, l + d)] = Ru[tri(l - 1, l - 1 + d)] -
                          head[l - 1] * head[l - 1 + d] +
                          win[l] * win[l + d];
  }

  // diagonal loading: += DL * trace/16
  float tr = 0.0f;
#pragma unroll
  for (int l = 0; l < 16; ++l) tr += Ru[tri(l, l)];
  const float dl = tr * (0.05f / 16.0f);
#pragma unroll
  for (int l = 0; l < 16; ++l) Ru[tri(l, l)] += dl;

  // x (unscaled window sums): X[l] = sum_{j=l}^{l+112} xf[j]
  float X[16];
  {
    float s = Sall;
#pragma unroll
    for (int i = 1; i < 16; ++i) s -= win[i];
    X[0] = s;
#pragma unroll
    for (int l = 1; l < 16; ++l) X[l] = X[l - 1] - head[l - 1] + win[l];
  }

  // ---- Cholesky R = L L^T (rsqrt form), L[i][j] at Ru[tri(j,i)] ----
  float inv[16];
#pragma unroll
  for (int j = 0; j < 16; ++j) {
    float d = Ru[tri(j, j)];
#pragma unroll
    for (int p = 0; p < j; ++p) d = fmaf(-Ru[tri(p, j)], Ru[tri(p, j)], d);
    inv[j] = rsqrtf(d);
#pragma unroll
    for (int i = j + 1; i < 16; ++i) {
      float s = Ru[tri(j, i)];
#pragma unroll
      for (int p = 0; p < j; ++p) s = fmaf(-Ru[tri(p, i)], Ru[tri(p, j)], s);
      Ru[tri(j, i)] = s * inv[j];
    }
  }

  // forward solve L y = 1
  float yv[16];
#pragma unroll
  for (int i = 0; i < 16; ++i) {
    float s = 1.0f;
#pragma unroll
    for (int j = 0; j < i; ++j) s = fmaf(-Ru[tri(j, i)], yv[j], s);
    yv[i] = s * inv[i];
  }
  // back solve L^T u = y
  float u[16];
#pragma unroll
  for (int i = 15; i >= 0; --i) {
    float s = yv[i];
#pragma unroll
    for (int j = i + 1; j < 16; ++j) s = fmaf(-Ru[tri(i, j)], u[j], s);
    u[i] = s * inv[i];
  }

  float su = 0.0f, dot = 0.0f;
#pragma unroll
  for (int i = 0; i < 16; ++i) {
    su += u[i];
    dot = fmaf(u[i], X[i], dot);
  }
  // y = dot/(M*su + 1e-10)  (matches reference up to scale algebra)
  out[pix] = dot / (113.0f * su + 1e-10f);
}

}  // namespace

extern "C" void kernel_launch(void* const* d_in, const int* in_sizes, int n_in,
                              void* d_out, int out_size, void* d_ws,
                              size_t ws_size, hipStream_t stream) {
  const float* rf   = (const float*)d_in[0];
  const float* t0   = (const float*)d_in[1];
  const float* d_tx = (const float*)d_in[2];
  const float* d_rx = (const float*)d_in[3];
  const float* fs   = (const float*)d_in[4];
  // d_in[5] = f0 (unused), d_in[7] = apod (unused by reference)
  const float* c0   = (const float*)d_in[6];
  float* out = (float*)d_out;

  hipLaunchKernelGGL(mvb_kernel, dim3(kB * kNZ / 2), dim3(kTPB), 0, stream,
                     rf, t0, d_tx, d_rx, fs, c0, out);
}

// Round 13
// 97.368 us; speedup vs baseline: 1.1186x; 1.1186x over previous
//
#include <hip/hip_runtime.h>

// MVB (minimum-variance beamformer), fp32. Round 13: R7's proven binary,
// mirror removed.
//
// R12 calibration: fixed harness overhead = 62 us (268 MB d_ws poison fill
// 43 us + restores + graph gaps). Per-unit kernel times: R5 fused 1w/SIMD
// ~33; R6 split LB(256,2) ~36 (VGPR-cap-handicapped); R7 = same kernel at
// LB(256,1) (VGPR=92) + mirror: 24.5/unit at 2 waves/SIMD -- the best
// measured. R12 SWP (VGPR 176): 47 -- worse. Conclusion: the R7 binary is
// the winner; this round runs it on real work only (grid 512, dst=out).
//
// Structure (verified R7, absmax 9.77e-4):
//  - block 256 = {lo,hi} channel halves x 128 px (one z-row); grid 512.
//  - rf staged to LDS in double-buffered 4-row-per-half (16 KB) steps via
//    global_load_lds; per-step __syncthreads; drx double-buffered in regs.
//  - per-half rolling 16-lag window sums; lo exports 49-float summary via
//    LDS; hi combines (cross-term algebra) + rsqrt-Cholesky + 2 triangular
//    solves + weighted sum.

namespace {

constexpr int kB  = 2;
constexpr int kC  = 128;
constexpr int kNS = 1024;
constexpr int kNZ = 256;
constexpr int kNX = 128;
constexpr int kZX = kNZ * kNX;        // 32768
constexpr int kHalfC = 64;            // channels per half
constexpr int kRows = 4;              // rf rows per half per step (16 KB)
constexpr int kBufF = 2 * kRows * kNS;  // floats per buffer (both halves)
constexpr int kTPB = 256;

// packed upper-triangular index, l <= k, 16x16 -> 136 entries
__device__ __host__ constexpr int tri(int l, int k) {
  return l * 16 - (l * (l - 1)) / 2 + (k - l);
}

typedef __attribute__((address_space(1))) const void gconst_t;
typedef __attribute__((address_space(3))) void ldsv_t;

__device__ __forceinline__ void g2l16(const float* g, float* l) {
  // 16B per lane, LDS dest = wave-uniform base + lane*16
  __builtin_amdgcn_global_load_lds((gconst_t*)g, (ldsv_t*)l, 16, 0, 0);
}

// Stage step q: lower half rows ch = q*4..q*4+3 (waves 0-1), upper half rows
// ch = 64+q*4.. (waves 2-3). Each wave: 8 issues x 1 KB = 8 KB. Async.
__device__ __forceinline__ void stage_step(const float* __restrict__ rfb,
                                           float* tbuf, int q, int wave,
                                           int lane) {
  const int h = wave >> 1;
  const int woff = (wave & 1) * 2048;          // floats within the 16 KB half
  const float* gsrc = rfb + (size_t)(h * kHalfC + q * kRows) * kNS;
  float* ldst = tbuf + h * (kRows * kNS);
#pragma unroll
  for (int i = 0; i < 8; ++i)
    g2l16(gsrc + woff + i * 256 + lane * 4, ldst + woff + i * 256);
}

__device__ __forceinline__ void load_drx4(const float* __restrict__ drxp,
                                          int cbase, float (&d)[kRows]) {
#pragma unroll
  for (int r = 0; r < kRows; ++r)
    d[r] = drxp[(size_t)(cbase + r) * kZX];    // coalesced across lanes
}

template <int PH, bool HEAD>
__device__ __forceinline__ void compute4(
    const float* rows, const float (&drx)[kRows], float kk, float base,
    float (&F)[16], float (&win)[16], float (&head)[16], float& Sall) {
#pragma unroll
  for (int r = 0; r < kRows; ++r) {
    const int t = PH + r;                      // local channel & 15 (static)
    float pos = fmaf(kk, drx[r], base);
    pos = fminf(fmaxf(pos, 0.0f), 1023.0f);
    int i0 = (int)pos;                         // pos >= 0: trunc == floor
    i0 = min(i0, kNS - 2);                     // pos==1023 -> frac==1.0
    float frac = pos - (float)i0;
    const float* p = rows + r * kNS + i0;
    float v0 = p[0];                           // ds_read2_b32 pair
    float v1 = p[1];
    float v = fmaf(frac, v1 - v0, v0);
    Sall += v;
    F[0] = fmaf(v, v, F[0]);
    if constexpr (HEAD) {
#pragma unroll
      for (int d = 1; d <= t; ++d) F[d] = fmaf(v, win[t - d], F[d]);
      head[t] = v;
    } else {
#pragma unroll
      for (int d = 1; d < 16; ++d) F[d] = fmaf(v, win[(t - d) & 15], F[d]);
    }
    win[t] = v;
  }
}

#define STEP(Q, PH, HEADF, CUR, NXT)                                       \
  do {                                                                     \
    if ((Q) + 1 < 16) {                                                    \
      stage_step(rfb, tile[((Q) + 1) & 1], (Q) + 1, wave, lane);           \
      load_drx4(drxp, ((Q) + 1) * kRows, NXT);                             \
    }                                                                      \
    compute4<PH, HEADF>(tile[(Q) & 1] + half * (kRows * kNS), CUR, kk,     \
                        base, F, win, head, Sall);                         \
    __syncthreads();                                                       \
  } while (0)

// ---------------- Fused kernel: split window + combine + solve -------------
__global__ __launch_bounds__(kTPB, 1) void mvb_fused_kernel(
    const float* __restrict__ rf, const float* __restrict__ t0,
    const float* __restrict__ d_tx, const float* __restrict__ d_rx,
    const float* __restrict__ fs_p, const float* __restrict__ c0_p,
    float* __restrict__ out) {
  __shared__ float tile[2][kBufF];     // 64 KB double buffer -> 2 blocks/CU

  const int tid = threadIdx.x;
  const int lane = tid & 63;
  const int wave = tid >> 6;
  const int half = tid >> 7;           // 0: ch 0-63, 1: ch 64-127
  const int px = tid & 127;
  const int z = blockIdx.x & (kNZ - 1);
  const int b = blockIdx.x >> 8;       // kNZ == 256
  const int pix = (int)((size_t)b * kZX + z * kNX + px);

  const float fs = fs_p[0];
  const float c0 = c0_p[0];
  const float kk = fs / c0;
  const float base = fs * (d_tx[pix] / c0 + t0[b]);

  const float* rfb = rf + (size_t)b * kC * kNS;
  const float* drxp =
      d_rx + (size_t)half * kHalfC * kZX + (size_t)z * kNX + px;

  float F[16], win[16], head[16];
  float Sall = 0.0f;
#pragma unroll
  for (int i = 0; i < 16; ++i) F[i] = 0.0f;

  float drxA[kRows], drxB[kRows];

  // ---- phase A: 16 steps of 4 channels per half, double-buffered ----
  stage_step(rfb, tile[0], 0, wave, lane);
  load_drx4(drxp, 0, drxA);
  __syncthreads();

  STEP(0, 0, true, drxA, drxB);
  STEP(1, 4, true, drxB, drxA);
  STEP(2, 8, true, drxA, drxB);
  STEP(3, 12, true, drxB, drxA);
#pragma unroll 1
  for (int g = 1; g < 4; ++g) {
    const int q = g * 4;
    STEP(q + 0, 0, false, drxA, drxB);
    STEP(q + 1, 4, false, drxB, drxA);
    STEP(q + 2, 8, false, drxA, drxB);
    STEP(q + 3, 12, false, drxB, drxA);
  }
  // per half: head[i] = x_{h*64+i}, win[i] = x_{h*64+48+i},
  //           F[d] = sum_{j in half, j-d in half} x_j x_{j-d}

  // ---- exchange: lo threads export their 49-float summary via dead LDS ----
  float* xch = tile[0];                // 49*128*4 B = 25 KB < 32 KB
  if (half == 0) {
#pragma unroll
    for (int i = 0; i < 16; ++i) xch[i * 128 + px] = F[i];
#pragma unroll
    for (int i = 0; i < 16; ++i) xch[(16 + i) * 128 + px] = win[i];
#pragma unroll
    for (int i = 0; i < 16; ++i) xch[(32 + i) * 128 + px] = head[i];
    xch[48 * 128 + px] = Sall;
  }
  __syncthreads();
  if (half == 0) return;               // hi threads combine + solve

  float hlo[16];                       // global head = lo's head
  {
    float wlo[16];
#pragma unroll
    for (int i = 0; i < 16; ++i) wlo[i] = xch[(16 + i) * 128 + px];
#pragma unroll
    for (int i = 0; i < 16; ++i) hlo[i] = xch[(32 + i) * 128 + px];
    Sall += xch[48 * 128 + px];
    F[0] += xch[0 * 128 + px];
#pragma unroll
    for (int d = 1; d < 16; ++d) {
      float s = xch[d * 128 + px];     // F_lo[d]
#pragma unroll
      for (int i = 0; i < d; ++i) s = fmaf(head[i], wlo[16 - d + i], s);
      F[d] += s;                       // + cross terms head_hi x win_lo
    }
  }
  // now: hlo = x_{0..15}, win = x_{112..127}, F[d] = full lag sums

  // ---- assemble R (unscaled; packed upper triangle) ----
  float Ru[136];
#pragma unroll
  for (int d = 0; d < 16; ++d) {
    float t0s = 0.0f;                  // tail beyond window of l=0
#pragma unroll
    for (int i = d + 1; i < 16; ++i) t0s = fmaf(win[i - d], win[i], t0s);
    Ru[tri(0, d)] = F[d] - t0s;
#pragma unroll
    for (int l = 1; l < 16 - d; ++l)
      Ru[tri(l, l + d)] = Ru[tri(l - 1, l - 1 + d)] -
                          hlo[l - 1] * hlo[l - 1 + d] +
                          win[l] * win[l + d];
  }

  // diagonal loading: += DL * trace/16
  float tr = 0.0f;
#pragma unroll
  for (int l = 0; l < 16; ++l) tr += Ru[tri(l, l)];
  const float dl = tr * (0.05f / 16.0f);
#pragma unroll
  for (int l = 0; l < 16; ++l) Ru[tri(l, l)] += dl;

  // x (unscaled window sums): X[l] = sum_{j=l}^{l+112} xf[j]
  float X[16];
  {
    float s = Sall;
#pragma unroll
    for (int i = 1; i < 16; ++i) s -= win[i];
    X[0] = s;
#pragma unroll
    for (int l = 1; l < 16; ++l) X[l] = X[l - 1] - hlo[l - 1] + win[l];
  }

  // ---- Cholesky R = L L^T (rsqrt form), L[i][j] at Ru[tri(j,i)] ----
  float inv[16];
#pragma unroll
  for (int j = 0; j < 16; ++j) {
    float d = Ru[tri(j, j)];
#pragma unroll
    for (int p = 0; p < j; ++p) d = fmaf(-Ru[tri(p, j)], Ru[tri(p, j)], d);
    inv[j] = rsqrtf(d);
#pragma unroll
    for (int i = j + 1; i < 16; ++i) {
      float s = Ru[tri(j, i)];
#pragma unroll
      for (int p = 0; p < j; ++p) s = fmaf(-Ru[tri(p, i)], Ru[tri(p, j)], s);
      Ru[tri(j, i)] = s * inv[j];
    }
  }

  // forward solve L y = 1
  float yv[16];
#pragma unroll
  for (int i = 0; i < 16; ++i) {
    float s = 1.0f;
#pragma unroll
    for (int j = 0; j < i; ++j) s = fmaf(-Ru[tri(j, i)], yv[j], s);
    yv[i] = s * inv[i];
  }
  // back solve L^T u = y
  float u[16];
#pragma unroll
  for (int i = 15; i >= 0; --i) {
    float s = yv[i];
#pragma unroll
    for (int j = i + 1; j < 16; ++j) s = fmaf(-Ru[tri(i, j)], u[j], s);
    u[i] = s * inv[i];
  }

  float su = 0.0f, dot = 0.0f;
#pragma unroll
  for (int i = 0; i < 16; ++i) {
    su += u[i];
    dot = fmaf(u[i], X[i], dot);
  }
  // y = dot/(M*su + 1e-10)  (matches reference up to scale algebra)
  out[pix] = dot / (113.0f * su + 1e-10f);
}

}  // namespace

extern "C" void kernel_launch(void* const* d_in, const int* in_sizes, int n_in,
                              void* d_out, int out_size, void* d_ws,
                              size_t ws_size, hipStream_t stream) {
  const float* rf   = (const float*)d_in[0];
  const float* t0   = (const float*)d_in[1];
  const float* d_tx = (const float*)d_in[2];
  const float* d_rx = (const float*)d_in[3];
  const float* fs   = (const float*)d_in[4];
  // d_in[5] = f0 (unused), d_in[7] = apod (unused by reference)
  const float* c0   = (const float*)d_in[6];
  float* out = (float*)d_out;

  hipLaunchKernelGGL(mvb_fused_kernel, dim3(kB * kNZ), dim3(kTPB), 0, stream,
                     rf, t0, d_tx, d_rx, fs, c0, out);
}

// Round 14
// 95.205 us; speedup vs baseline: 1.1440x; 1.0227x over previous
//
#include <hip/hip_runtime.h>

// MVB (minimum-variance beamformer), fp32. Round 14: final — reproduce R10,
// the best-measured configuration (94.6 us).
//
// Session findings (R0-R13):
//  - Harness floor ~95 us: 43 us d_ws 0xAA poison fill (268 MB @ 6.2 TB/s)
//    + input restores + graph gaps. Kernels <= ~33 us hide inside it:
//    R13's 24.5-us kernel gave a WORSE total (97.4) than R10's 33-us kernel
//    (94.6). Kernel-side deltas below ~5 us are unresolvable by this bench.
//  - Best per-unit kernel: R7 structure (channel-split LDS, LB(256,1),
//    VGPR=92), 24.5 us/unit. Best total: THIS kernel (R10).
//  - Dead ends with evidence: lambda-captured register arrays -> SROA
//    scratch demotion (R1/R2, 122 MB spill traffic); manual vmcnt pipelines
//    regress or break correctness (R8/R12); LB(256,2) VGPR cap handicaps
//    codegen (R6 vs R7); TLP/barrier changes all land within noise.
//
// Structure: 1 thread/pixel, no LDS, no barriers. 8 chunks x 16 channels:
// 16 coalesced drx loads -> 16 independent 8-B gathers from L1/L2-resident
// rf (global_load_dwordx2, 32 in flight) -> static-index rolling 16-lag
// window FMAs. R via lag identity (F[d] minus head/tail corrections),
// 1/M dropped (scale-invariant), diag loading, rsqrt-Cholesky, two
// triangular solves, weighted sum. absmax 9.77e-4 (threshold 6.3e-3).

namespace {

constexpr int kB  = 2;
constexpr int kC  = 128;
constexpr int kNS = 1024;
constexpr int kNZ = 256;
constexpr int kNX = 128;
constexpr int kZX = kNZ * kNX;        // 32768
constexpr int kTPB = 256;

// packed upper-triangular index, l <= k, 16x16 -> 136 entries
__device__ __host__ constexpr int tri(int l, int k) {
  return l * 16 - (l * (l - 1)) / 2 + (k - l);
}

template <bool HEAD>
__device__ __forceinline__ void chunk16(
    const float* __restrict__ rfq,       // rfb + q*16*kNS
    const float* __restrict__ drxp, int cbase, float kk, float base,
    float (&F)[16], float (&win)[16], float (&head)[16], float& Sall) {
  // 16 coalesced per-channel delays (independent, deep in flight)
  float dr[16];
#pragma unroll
  for (int r = 0; r < 16; ++r) dr[r] = drxp[(size_t)(cbase + r) * kZX];

  // 16 independent 8-byte gathers from the L1/L2-resident rf rows
  float2 vv[16];
  float fr[16];
#pragma unroll
  for (int r = 0; r < 16; ++r) {
    float pos = fmaf(kk, dr[r], base);
    pos = fminf(fmaxf(pos, 0.0f), 1023.0f);
    int i0 = (int)pos;                   // pos >= 0: trunc == floor
    i0 = min(i0, kNS - 2);               // pos==1023 -> frac==1.0
    fr[r] = pos - (float)i0;
    __builtin_memcpy(&vv[r], rfq + r * kNS + i0, 8);   // v0,v1 adjacent
  }

  // window-FMA bursts; chunk aligns with L_SUB so indices are static
#pragma unroll
  for (int r = 0; r < 16; ++r) {
    float v = fmaf(fr[r], vv[r].y - vv[r].x, vv[r].x);
    Sall += v;
    F[0] = fmaf(v, v, F[0]);
    if constexpr (HEAD) {
#pragma unroll
      for (int d = 1; d <= r; ++d) F[d] = fmaf(v, win[r - d], F[d]);
      head[r] = v;
    } else {
#pragma unroll
      for (int d = 1; d < 16; ++d) F[d] = fmaf(v, win[(r - d) & 15], F[d]);
    }
    win[r] = v;
  }
}

// ---------------- Fused kernel: gather + window + solve, no LDS ------------
__global__ __launch_bounds__(kTPB, 1) void mvb_kernel(
    const float* __restrict__ rf, const float* __restrict__ t0,
    const float* __restrict__ d_tx, const float* __restrict__ d_rx,
    const float* __restrict__ fs_p, const float* __restrict__ c0_p,
    float* __restrict__ out) {
  const int tid = threadIdx.x;
  const int b = blockIdx.x >> 7;         // 256 blocks: b in {0,1}
  const int z = ((blockIdx.x & 127) << 1) + (tid >> 7);
  const int x = tid & 127;
  const int pix = (int)((size_t)b * kZX + z * kNX + x);

  const float fs = fs_p[0];
  const float c0 = c0_p[0];
  const float kk = fs / c0;
  const float base = fs * (d_tx[pix] / c0 + t0[b]);

  const float* rfb = rf + (size_t)b * kC * kNS;
  const float* drxp = d_rx + (size_t)z * kNX + x;   // + c*kZX per channel

  float F[16], win[16], head[16];
  float Sall = 0.0f;
#pragma unroll
  for (int i = 0; i < 16; ++i) F[i] = 0.0f;

  // ---- phase A: 8 chunks of 16 channels ----
  chunk16<true>(rfb, drxp, 0, kk, base, F, win, head, Sall);
#pragma unroll 1
  for (int q = 1; q < 8; ++q)
    chunk16<false>(rfb + (size_t)q * 16 * kNS, drxp, q * 16, kk, base, F, win,
                   head, Sall);
  // now: head[i] = xf[i], win[i] = xf[112+i], F[d] = sum_j xf[j]*xf[j-d]

  // ---- assemble R (unscaled; packed upper triangle) ----
  float Ru[136];
#pragma unroll
  for (int d = 0; d < 16; ++d) {
    float t0s = 0.0f;                    // tail beyond window of l=0
#pragma unroll
    for (int i = d + 1; i < 16; ++i) t0s = fmaf(win[i - d], win[i], t0s);
    Ru[tri(0, d)] = F[d] - t0s;
#pragma unroll
    for (int l = 1; l < 16 - d; ++l)
      Ru[tri(l, l + d)] = Ru[tri(l - 1, l - 1 + d)] -
                          head[l - 1] * head[l - 1 + d] +
                          win[l] * win[l + d];
  }

  // diagonal loading: += DL * trace/16
  float tr = 0.0f;
#pragma unroll
  for (int l = 0; l < 16; ++l) tr += Ru[tri(l, l)];
  const float dl = tr * (0.05f / 16.0f);
#pragma unroll
  for (int l = 0; l < 16; ++l) Ru[tri(l, l)] += dl;

  // x (unscaled window sums): X[l] = sum_{j=l}^{l+112} xf[j]
  float X[16];
  {
    float s = Sall;
#pragma unroll
    for (int i = 1; i < 16; ++i) s -= win[i];
    X[0] = s;
#pragma unroll
    for (int l = 1; l < 16; ++l) X[l] = X[l - 1] - head[l - 1] + win[l];
  }

  // ---- Cholesky R = L L^T (rsqrt form), L[i][j] at Ru[tri(j,i)] ----
  float inv[16];
#pragma unroll
  for (int j = 0; j < 16; ++j) {
    float d = Ru[tri(j, j)];
#pragma unroll
    for (int p = 0; p < j; ++p) d = fmaf(-Ru[tri(p, j)], Ru[tri(p, j)], d);
    inv[j] = rsqrtf(d);
#pragma unroll
    for (int i = j + 1; i < 16; ++i) {
      float s = Ru[tri(j, i)];
#pragma unroll
      for (int p = 0; p < j; ++p) s = fmaf(-Ru[tri(p, i)], Ru[tri(p, j)], s);
      Ru[tri(j, i)] = s * inv[j];
    }
  }

  // forward solve L y = 1
  float yv[16];
#pragma unroll
  for (int i = 0; i < 16; ++i) {
    float s = 1.0f;
#pragma unroll
    for (int j = 0; j < i; ++j) s = fmaf(-Ru[tri(j, i)], yv[j], s);
    yv[i] = s * inv[i];
  }
  // back solve L^T u = y
  float u[16];
#pragma unroll
  for (int i = 15; i >= 0; --i) {
    float s = yv[i];
#pragma unroll
    for (int j = i + 1; j < 16; ++j) s = fmaf(-Ru[tri(i, j)], u[j], s);
    u[i] = s * inv[i];
  }

  float su = 0.0f, dot = 0.0f;
#pragma unroll
  for (int i = 0; i < 16; ++i) {
    su += u[i];
    dot = fmaf(u[i], X[i], dot);
  }
  // y = dot/(M*su + 1e-10)  (matches reference up to scale algebra)
  out[pix] = dot / (113.0f * su + 1e-10f);
}

}  // namespace

extern "C" void kernel_launch(void* const* d_in, const int* in_sizes, int n_in,
                              void* d_out, int out_size, void* d_ws,
                              size_t ws_size, hipStream_t stream) {
  const float* rf   = (const float*)d_in[0];
  const float* t0   = (const float*)d_in[1];
  const float* d_tx = (const float*)d_in[2];
  const float* d_rx = (const float*)d_in[3];
  const float* fs   = (const float*)d_in[4];
  // d_in[5] = f0 (unused), d_in[7] = apod (unused by reference)
  const float* c0   = (const float*)d_in[6];
  float* out = (float*)d_out;

  hipLaunchKernelGGL(mvb_kernel, dim3(kB * kNZ / 2), dim3(kTPB), 0, stream,
                     rf, t0, d_tx, d_rx, fs, c0, out);
}